// Round 10
// baseline (147.921 us; speedup 1.0000x reference)
//
#include <hip/hip_runtime.h>

#define TPB 512
#define QPT 8            // queries per thread = 4 packed chains
#define NCH (QPT / 2)
#define NSEG 32          // ref-dimension split

typedef float v2f __attribute__((ext_vector_type(2)));

// Refs stored pre-duplicated: {x,x},{y,y},{z,z},{w,w} — each double is an
// SGPR-pair broadcast operand for VOP3P packed math (1 scalar operand/instr).
struct RefDup { double x2, y2, z2, w2; };

// Order-preserving float<->uint encoding so atomicMin(uint) == float min.
__device__ __forceinline__ unsigned encf(float f) {
    unsigned u = __float_as_uint(f);
    return (u & 0x80000000u) ? ~u : (u | 0x80000000u);
}
__device__ __forceinline__ float decf(unsigned u) {
    return __uint_as_float((u & 0x80000000u) ? (u ^ 0x80000000u) : ~u);
}
__device__ __forceinline__ double dup2(float v) {
    union { float f[2]; double d; } u; u.f[0] = v; u.f[1] = v; return u.d;
}

// v_pk_fma_f32: D = S0*S1 + S2 per 32-bit half; S1 = wave-uniform SGPR pair.
// (VOP3P f32 ops need 64-bit operands; single-VGPR broadcast is NOT legal.)
__device__ __forceinline__ v2f pk_fma_vs(v2f a, double b, v2f c) {
    v2f d; asm("v_pk_fma_f32 %0, %1, %2, %3" : "=v"(d) : "v"(a), "s"(b), "v"(c)); return d;
}

// Pack both inputs into duplicated layout; init umins to +max.
__global__ void __launch_bounds__(256) prep(const float* __restrict__ preds,
                                            const float* __restrict__ gts,
                                            RefDup* __restrict__ P8,
                                            RefDup* __restrict__ G8,
                                            unsigned* __restrict__ umins,
                                            int totalP, int totalG, int totalU) {
    int i = blockIdx.x * blockDim.x + threadIdx.x;
    if (i < totalP) {
        float x = preds[3 * i], y = preds[3 * i + 1], z = preds[3 * i + 2];
        RefDup r;
        r.x2 = dup2(x); r.y2 = dup2(y); r.z2 = dup2(z);
        r.w2 = dup2(fmaf(x, x, fmaf(y, y, z * z)));
        P8[i] = r;
    } else if (i < totalP + totalG) {
        int k = i - totalP;
        float x = gts[3 * k], y = gts[3 * k + 1], z = gts[3 * k + 2];
        RefDup r;
        r.x2 = dup2(x); r.y2 = dup2(y); r.z2 = dup2(z);
        r.w2 = dup2(fmaf(x, x, fmaf(y, y, z * z)));
        G8[k] = r;
    }
    if (i < totalU) umins[i] = 0xFFFFFFFFu;  // encodes +max — identity for min
}

// Round-7 proven core + per-wave stagger: wave w starts its ref scan at
// s0 + w*(segLen/8) and wraps, de-correlating the 8 waves' scalar-cache
// misses (they otherwise convoy on identical addresses and stall together).
__global__ void __launch_bounds__(TPB, 4) chamfer_dir(const RefDup* __restrict__ P8,
                                                      const RefDup* __restrict__ G8,
                                                      unsigned* __restrict__ umins,
                                                      int N, int M, int B, int nQpad) {
    const int db  = blockIdx.z;          // dir*B + b
    const int dir = db / B;
    const int b   = db - dir * B;
    const int seg = blockIdx.y;

    const RefDup* __restrict__ Qd = (dir == 0) ? (P8 + (size_t)b * N) : (G8 + (size_t)b * M);
    const RefDup* __restrict__ R  = (dir == 0) ? (G8 + (size_t)b * M) : (P8 + (size_t)b * N);
    const int nQ = (dir == 0) ? N : M;
    const int nR = (dir == 0) ? M : N;

    const int segLen = (nR + NSEG - 1) / NSEG;
    const int s0 = seg * segLen;
    const int s1 = (s0 + segLen < nR) ? (s0 + segLen) : nR;
    if (s0 >= s1) return;

    const int qbase = blockIdx.x * (TPB * QPT) + (int)threadIdx.x;

    // Chain c holds queries (qbase+2c*TPB, qbase+(2c+1)*TPB) in lo/hi halves,
    // coords pre-scaled by -2 so d = fma(qx,rx, fma(qy,ry, fma(qz,rz, rw))).
    v2f qx2[NCH], qy2[NCH], qz2[NCH], pw2[NCH], m2[NCH];
    #pragma unroll
    for (int c = 0; c < NCH; ++c) {
        const int qa = qbase + (2 * c) * TPB;
        const int qb = qbase + (2 * c + 1) * TPB;
        const int qac = (qa < nQ) ? qa : 0;   // clamp; guarded at the atomic
        const int qbc = (qb < nQ) ? qb : 0;
        const float* fa = (const float*)&Qd[qac];  // {x,x,y,y,z,z,w,w}
        const float* fb = (const float*)&Qd[qbc];
        qx2[c].x = -2.f * fa[0]; qx2[c].y = -2.f * fb[0];
        qy2[c].x = -2.f * fa[2]; qy2[c].y = -2.f * fb[2];
        qz2[c].x = -2.f * fa[4]; qz2[c].y = -2.f * fb[4];
        pw2[c].x = fa[6];        pw2[c].y = fb[6];
        m2[c].x = 3.4e38f;       m2[c].y = 3.4e38f;
    }

    auto dupw = [](double w) -> v2f {   // w -> VGPR pair, shared by all chains
        union { double d; float f[2]; } u; u.d = w;
        v2f r; r.x = u.f[0]; r.y = u.f[1]; return r;
    };

    auto step4 = [&](const RefDup& r0, const RefDup& r1,
                     const RefDup& r2, const RefDup& r3) {
        v2f w0 = dupw(r0.w2), w1 = dupw(r1.w2), w2v = dupw(r2.w2), w3 = dupw(r3.w2);
        #pragma unroll
        for (int c = 0; c < NCH; ++c) {
            v2f d0 = pk_fma_vs(qz2[c], r0.z2, w0);
            d0 = pk_fma_vs(qy2[c], r0.y2, d0);
            d0 = pk_fma_vs(qx2[c], r0.x2, d0);
            v2f d1 = pk_fma_vs(qz2[c], r1.z2, w1);
            d1 = pk_fma_vs(qy2[c], r1.y2, d1);
            d1 = pk_fma_vs(qx2[c], r1.x2, d1);
            v2f d2 = pk_fma_vs(qz2[c], r2.z2, w2v);
            d2 = pk_fma_vs(qy2[c], r2.y2, d2);
            d2 = pk_fma_vs(qx2[c], r2.x2, d2);
            v2f d3 = pk_fma_vs(qz2[c], r3.z2, w3);
            d3 = pk_fma_vs(qy2[c], r3.y2, d3);
            d3 = pk_fma_vs(qx2[c], r3.x2, d3);
            m2[c].x = fminf(fminf(m2[c].x, d0.x), d1.x);  // -> v_min3_f32
            m2[c].y = fminf(fminf(m2[c].y, d0.y), d1.y);
            m2[c].x = fminf(fminf(m2[c].x, d2.x), d3.x);
            m2[c].y = fminf(fminf(m2[c].y, d2.y), d3.y);
        }
    };

    auto step1 = [&](const RefDup& r) {
        v2f wv = dupw(r.w2);
        #pragma unroll
        for (int c = 0; c < NCH; ++c) {
            v2f d = pk_fma_vs(qz2[c], r.z2, wv);
            d = pk_fma_vs(qy2[c], r.y2, d);
            d = pk_fma_vs(qx2[c], r.x2, d);
            m2[c].x = fminf(m2[c].x, d.x);
            m2[c].y = fminf(m2[c].y, d.y);
        }
    };

    // Scan [lo, hi) with 1-quad rotating prefetch (round-7 proven).
    auto scan = [&](int lo, int hi) {
        int i = lo;
        if (hi - lo >= 8) {
            RefDup r0 = R[i + 0], r1 = R[i + 1], r2 = R[i + 2], r3 = R[i + 3];
            for (; i + 8 <= hi; i += 4) {
                RefDup n0 = R[i + 4], n1 = R[i + 5], n2 = R[i + 6], n3 = R[i + 7];
                step4(r0, r1, r2, r3);
                r0 = n0; r1 = n1; r2 = n2; r3 = n3;
            }
            step4(r0, r1, r2, r3);
            i += 4;
        }
        for (; i < hi; ++i) step1(R[i]);
    };

    // Per-wave stagger (wrap): wave w covers [start,s1) then [s0,start).
    const int wid = (int)threadIdx.x >> 6;
    int off = ((s1 - s0) >> 3) & ~3;          // quarter... eighth of segment, /4 aligned
    int start = s0 + wid * off;
    if (start > s1) start = s1;
    scan(start, s1);
    scan(s0, start);

    // Low-contention atomics (proven ~4B HBM each, ~16MB total).
    unsigned* __restrict__ dst = umins + (size_t)db * nQpad;
    #pragma unroll
    for (int c = 0; c < NCH; ++c) {
        const int qa = qbase + (2 * c) * TPB;
        const int qb = qbase + (2 * c + 1) * TPB;
        if (qa < nQ) atomicMin(&dst[qa], encf(m2[c].x + pw2[c].x));
        if (qb < nQ) atomicMin(&dst[qb], encf(m2[c].y + pw2[c].y));
    }
}

// One block per batch b: decode + fixed-order sums for both directions.
__global__ void __launch_bounds__(256) finish(const unsigned* __restrict__ umins,
                                              float* __restrict__ out,
                                              int N, int M, int B, int nQpad) {
    const int b = blockIdx.x;
    const unsigned* m0 = umins + (size_t)b * nQpad;            // dir 0 (per-pred)
    const unsigned* m1 = umins + (size_t)(B + b) * nQpad;      // dir 1 (per-gt)

    float s0 = 0.f, s1 = 0.f;
    for (int q = (int)threadIdx.x; q < N; q += 256) s0 += decf(m0[q]);
    for (int q = (int)threadIdx.x; q < M; q += 256) s1 += decf(m1[q]);

    for (int off = 32; off > 0; off >>= 1) {
        s0 += __shfl_down(s0, off);
        s1 += __shfl_down(s1, off);
    }
    __shared__ float r0s[4], r1s[4];
    const int wid  = (int)threadIdx.x >> 6;
    const int lane = (int)threadIdx.x & 63;
    if (lane == 0) { r0s[wid] = s0; r1s[wid] = s1; }
    __syncthreads();
    if (threadIdx.x == 0) {
        float S0 = 0.f, S1 = 0.f;
        #pragma unroll
        for (int w = 0; w < 4; ++w) { S0 += r0s[w]; S1 += r1s[w]; }
        out[b] = S0 / (float)N + S1 / (float)M;
    }
}

extern "C" void kernel_launch(void* const* d_in, const int* in_sizes, int n_in,
                              void* d_out, int out_size, void* d_ws, size_t ws_size,
                              hipStream_t stream) {
    const float* preds = (const float*)d_in[0];  // [B, N, 3]
    const float* gts   = (const float*)d_in[1];  // [B, M, 3]
    float* out = (float*)d_out;                  // [B]

    const int B = out_size;                      // 8
    const int N = in_sizes[0] / (B * 3);         // 8192
    const int M = in_sizes[1] / (B * 3);         // 8192
    const int nQpad = (N > M ? N : M);

    RefDup*   P8    = (RefDup*)d_ws;                     // [B*N]  (32 B each)
    RefDup*   G8    = P8 + (size_t)B * N;                // [B*M]
    unsigned* umins = (unsigned*)(G8 + (size_t)B * M);   // [2*B][nQpad]

    const int totalP = B * N;
    const int totalG = B * M;
    const int totalU = 2 * B * nQpad;
    const int prepTot = (totalP + totalG > totalU) ? (totalP + totalG) : totalU;
    prep<<<(prepTot + 255) / 256, 256, 0, stream>>>(preds, gts, P8, G8, umins,
                                                    totalP, totalG, totalU);

    const int qChunks = (nQpad + TPB * QPT - 1) / (TPB * QPT);  // 2
    dim3 grid(qChunks, NSEG, 2 * B);                            // 2*32*16 = 1024
    chamfer_dir<<<grid, TPB, 0, stream>>>(P8, G8, umins, N, M, B, nQpad);

    finish<<<B, 256, 0, stream>>>(umins, out, N, M, B, nQpad);
}

// Round 11
// 125.989 us; speedup vs baseline: 1.1741x; 1.1741x over previous
//
#include <hip/hip_runtime.h>

#define TPB 512
#define QPT 8            // queries per thread = 4 packed chains
#define NCH (QPT / 2)
#define NSEG 32          // ref-dimension split (segLen = 256 for 8192)
#define SEGCAP 256       // refs per LDS chunk (8 KB)

typedef float v2f __attribute__((ext_vector_type(2)));

// Refs stored pre-duplicated: {x,x},{y,y},{z,z},{w,w} (32 B) — consumed from
// LDS as VGPR pairs, so v_pk_fma_f32 runs with all-VGPR operands (no movs).
struct RefDup { double x2, y2, z2, w2; };

// Order-preserving float<->uint encoding so atomicMin(uint) == float min.
__device__ __forceinline__ unsigned encf(float f) {
    unsigned u = __float_as_uint(f);
    return (u & 0x80000000u) ? ~u : (u | 0x80000000u);
}
__device__ __forceinline__ float decf(unsigned u) {
    return __uint_as_float((u & 0x80000000u) ? (u ^ 0x80000000u) : ~u);
}
__device__ __forceinline__ double dup2(float v) {
    union { float f[2]; double d; } u; u.f[0] = v; u.f[1] = v; return u.d;
}

// v_pk_fma_f32, all-VGPR operands: D = S0*S1 + S2 per 32-bit half.
__device__ __forceinline__ v2f pk_fma_vv(v2f a, v2f b, v2f c) {
    v2f d; asm("v_pk_fma_f32 %0, %1, %2, %3" : "=v"(d) : "v"(a), "v"(b), "v"(c)); return d;
}

// Pack both inputs into duplicated layout; init umins to +max.
__global__ void __launch_bounds__(256) prep(const float* __restrict__ preds,
                                            const float* __restrict__ gts,
                                            RefDup* __restrict__ P8,
                                            RefDup* __restrict__ G8,
                                            unsigned* __restrict__ umins,
                                            int totalP, int totalG, int totalU) {
    int i = blockIdx.x * blockDim.x + threadIdx.x;
    if (i < totalP) {
        float x = preds[3 * i], y = preds[3 * i + 1], z = preds[3 * i + 2];
        RefDup r;
        r.x2 = dup2(x); r.y2 = dup2(y); r.z2 = dup2(z);
        r.w2 = dup2(fmaf(x, x, fmaf(y, y, z * z)));
        P8[i] = r;
    } else if (i < totalP + totalG) {
        int k = i - totalP;
        float x = gts[3 * k], y = gts[3 * k + 1], z = gts[3 * k + 2];
        RefDup r;
        r.x2 = dup2(x); r.y2 = dup2(y); r.z2 = dup2(z);
        r.w2 = dup2(fmaf(x, x, fmaf(y, y, z * z)));
        G8[k] = r;
    }
    if (i < totalU) umins[i] = 0xFFFFFFFFu;  // encodes +max — identity for min
}

// One quad of refs resident in VGPRs (4 refs x 4 pairs = 32 VGPRs).
struct Quad {
    v2f x0, y0, z0, w0, x1, y1, z1, w1, x2, y2, z2, w2, x3, y3, z3, w3;
};
__device__ __forceinline__ Quad loadQuad(const v2f* __restrict__ L, int i) {
    Quad q;
    q.x0 = L[4 * i + 0];  q.y0 = L[4 * i + 1];  q.z0 = L[4 * i + 2];  q.w0 = L[4 * i + 3];
    q.x1 = L[4 * i + 4];  q.y1 = L[4 * i + 5];  q.z1 = L[4 * i + 6];  q.w1 = L[4 * i + 7];
    q.x2 = L[4 * i + 8];  q.y2 = L[4 * i + 9];  q.z2 = L[4 * i + 10]; q.w2 = L[4 * i + 11];
    q.x3 = L[4 * i + 12]; q.y3 = L[4 * i + 13]; q.z3 = L[4 * i + 14]; q.w3 = L[4 * i + 15];
    return q;
}

// Round-7 geometry (proven 94.5us): grid (qChunks, NSEG, 2*B), QPT=8 packed
// queries/thread. Change: refs come from LDS (uniform ds_read broadcast) as
// VGPR pairs; inner quad = 8 ds_read + 48 pk_fma + 16 min3, zero movs, no SMEM.
__global__ void __launch_bounds__(TPB, 4) chamfer_dir(const RefDup* __restrict__ P8,
                                                      const RefDup* __restrict__ G8,
                                                      unsigned* __restrict__ umins,
                                                      int N, int M, int B, int nQpad) {
    const int db  = blockIdx.z;          // dir*B + b
    const int dir = db / B;
    const int b   = db - dir * B;
    const int seg = blockIdx.y;

    const RefDup* __restrict__ Qd = (dir == 0) ? (P8 + (size_t)b * N) : (G8 + (size_t)b * M);
    const RefDup* __restrict__ R  = (dir == 0) ? (G8 + (size_t)b * M) : (P8 + (size_t)b * N);
    const int nQ = (dir == 0) ? N : M;
    const int nR = (dir == 0) ? M : N;

    const int segLen = (nR + NSEG - 1) / NSEG;
    const int s0 = seg * segLen;
    const int s1 = (s0 + segLen < nR) ? (s0 + segLen) : nR;
    if (s0 >= s1) return;

    const int qbase = blockIdx.x * (TPB * QPT) + (int)threadIdx.x;

    // Chain c holds queries (qbase+2c*TPB, qbase+(2c+1)*TPB) in lo/hi halves,
    // coords pre-scaled by -2 so d = fma(qx,rx, fma(qy,ry, fma(qz,rz, rw))).
    v2f qx2[NCH], qy2[NCH], qz2[NCH], pw2[NCH], m2[NCH];
    #pragma unroll
    for (int c = 0; c < NCH; ++c) {
        const int qa = qbase + (2 * c) * TPB;
        const int qb = qbase + (2 * c + 1) * TPB;
        const int qac = (qa < nQ) ? qa : 0;   // clamp; guarded at the atomic
        const int qbc = (qb < nQ) ? qb : 0;
        const float* fa = (const float*)&Qd[qac];  // {x,x,y,y,z,z,w,w}
        const float* fb = (const float*)&Qd[qbc];
        qx2[c].x = -2.f * fa[0]; qx2[c].y = -2.f * fb[0];
        qy2[c].x = -2.f * fa[2]; qy2[c].y = -2.f * fb[2];
        qz2[c].x = -2.f * fa[4]; qz2[c].y = -2.f * fb[4];
        pw2[c].x = fa[6];        pw2[c].y = fb[6];
        m2[c].x = 3.4e38f;       m2[c].y = 3.4e38f;
    }

    __shared__ float4 ldsbuf[SEGCAP * 2];    // 8 KB: SEGCAP RefDups
    const v2f* __restrict__ L = (const v2f*)ldsbuf;

#define CHAINS(q)                                                              \
    do {                                                                       \
        _Pragma("unroll")                                                      \
        for (int c = 0; c < NCH; ++c) {                                        \
            v2f d0 = pk_fma_vv(qz2[c], (q).z0, (q).w0);                        \
            d0 = pk_fma_vv(qy2[c], (q).y0, d0);                                \
            d0 = pk_fma_vv(qx2[c], (q).x0, d0);                                \
            v2f d1 = pk_fma_vv(qz2[c], (q).z1, (q).w1);                        \
            d1 = pk_fma_vv(qy2[c], (q).y1, d1);                                \
            d1 = pk_fma_vv(qx2[c], (q).x1, d1);                                \
            v2f d2 = pk_fma_vv(qz2[c], (q).z2, (q).w2);                        \
            d2 = pk_fma_vv(qy2[c], (q).y2, d2);                                \
            d2 = pk_fma_vv(qx2[c], (q).x2, d2);                                \
            v2f d3 = pk_fma_vv(qz2[c], (q).z3, (q).w3);                        \
            d3 = pk_fma_vv(qy2[c], (q).y3, d3);                                \
            d3 = pk_fma_vv(qx2[c], (q).x3, d3);                                \
            m2[c].x = fminf(fminf(m2[c].x, d0.x), d1.x);  /* v_min3_f32 */     \
            m2[c].y = fminf(fminf(m2[c].y, d0.y), d1.y);                       \
            m2[c].x = fminf(fminf(m2[c].x, d2.x), d3.x);                       \
            m2[c].y = fminf(fminf(m2[c].y, d2.y), d3.y);                       \
        }                                                                      \
    } while (0)

    for (int t0 = s0; t0 < s1; t0 += SEGCAP) {
        const int t1 = (t0 + SEGCAP < s1) ? (t0 + SEGCAP) : s1;
        const int len = t1 - t0;

        // Stage chunk: one float4 per thread slot (coalesced, 8 KB).
        __syncthreads();                      // previous chunk fully consumed
        const float4* __restrict__ Rv = (const float4*)(R + t0);
        for (int t = (int)threadIdx.x; t < 2 * len; t += TPB) ldsbuf[t] = Rv[t];
        __syncthreads();

        int i = 0;
        if (len >= 8) {
            // A/B software pipeline: ds_reads for one quad in flight under the
            // previous quad's 48 pk_fma (~224 exec cycles >> ds latency).
            Quad A = loadQuad(L, 0);
            Quad Bq = loadQuad(L, 4);
            for (; i + 16 <= len; i += 8) {
                CHAINS(A);  A  = loadQuad(L, i + 8);
                CHAINS(Bq); Bq = loadQuad(L, i + 12);
            }
            CHAINS(A);
            CHAINS(Bq);
            i += 8;
        }
        for (; i < len; ++i) {
            v2f rx = L[4 * i + 0], ry = L[4 * i + 1], rz = L[4 * i + 2], rw = L[4 * i + 3];
            #pragma unroll
            for (int c = 0; c < NCH; ++c) {
                v2f d = pk_fma_vv(qz2[c], rz, rw);
                d = pk_fma_vv(qy2[c], ry, d);
                d = pk_fma_vv(qx2[c], rx, d);
                m2[c].x = fminf(m2[c].x, d.x);
                m2[c].y = fminf(m2[c].y, d.y);
            }
        }
    }
#undef CHAINS

    // Low-contention atomics (proven ~4B HBM each, ~16MB total).
    unsigned* __restrict__ dst = umins + (size_t)db * nQpad;
    #pragma unroll
    for (int c = 0; c < NCH; ++c) {
        const int qa = qbase + (2 * c) * TPB;
        const int qb = qbase + (2 * c + 1) * TPB;
        if (qa < nQ) atomicMin(&dst[qa], encf(m2[c].x + pw2[c].x));
        if (qb < nQ) atomicMin(&dst[qb], encf(m2[c].y + pw2[c].y));
    }
}

// One block per batch b: decode + fixed-order sums for both directions.
__global__ void __launch_bounds__(256) finish(const unsigned* __restrict__ umins,
                                              float* __restrict__ out,
                                              int N, int M, int B, int nQpad) {
    const int b = blockIdx.x;
    const unsigned* m0 = umins + (size_t)b * nQpad;            // dir 0 (per-pred)
    const unsigned* m1 = umins + (size_t)(B + b) * nQpad;      // dir 1 (per-gt)

    float s0 = 0.f, s1 = 0.f;
    for (int q = (int)threadIdx.x; q < N; q += 256) s0 += decf(m0[q]);
    for (int q = (int)threadIdx.x; q < M; q += 256) s1 += decf(m1[q]);

    for (int off = 32; off > 0; off >>= 1) {
        s0 += __shfl_down(s0, off);
        s1 += __shfl_down(s1, off);
    }
    __shared__ float r0s[4], r1s[4];
    const int wid  = (int)threadIdx.x >> 6;
    const int lane = (int)threadIdx.x & 63;
    if (lane == 0) { r0s[wid] = s0; r1s[wid] = s1; }
    __syncthreads();
    if (threadIdx.x == 0) {
        float S0 = 0.f, S1 = 0.f;
        #pragma unroll
        for (int w = 0; w < 4; ++w) { S0 += r0s[w]; S1 += r1s[w]; }
        out[b] = S0 / (float)N + S1 / (float)M;
    }
}

extern "C" void kernel_launch(void* const* d_in, const int* in_sizes, int n_in,
                              void* d_out, int out_size, void* d_ws, size_t ws_size,
                              hipStream_t stream) {
    const float* preds = (const float*)d_in[0];  // [B, N, 3]
    const float* gts   = (const float*)d_in[1];  // [B, M, 3]
    float* out = (float*)d_out;                  // [B]

    const int B = out_size;                      // 8
    const int N = in_sizes[0] / (B * 3);         // 8192
    const int M = in_sizes[1] / (B * 3);         // 8192
    const int nQpad = (N > M ? N : M);

    RefDup*   P8    = (RefDup*)d_ws;                     // [B*N]  (32 B each)
    RefDup*   G8    = P8 + (size_t)B * N;                // [B*M]
    unsigned* umins = (unsigned*)(G8 + (size_t)B * M);   // [2*B][nQpad]

    const int totalP = B * N;
    const int totalG = B * M;
    const int totalU = 2 * B * nQpad;
    const int prepTot = (totalP + totalG > totalU) ? (totalP + totalG) : totalU;
    prep<<<(prepTot + 255) / 256, 256, 0, stream>>>(preds, gts, P8, G8, umins,
                                                    totalP, totalG, totalU);

    const int qChunks = (nQpad + TPB * QPT - 1) / (TPB * QPT);  // 2
    dim3 grid(qChunks, NSEG, 2 * B);                            // 2*32*16 = 1024
    chamfer_dir<<<grid, TPB, 0, stream>>>(P8, G8, umins, N, M, B, nQpad);

    finish<<<B, 256, 0, stream>>>(umins, out, N, M, B, nQpad);
}